// Round 3
// baseline (411.274 us; speedup 1.0000x reference)
//
#include <hip/hip_runtime.h>
#include <stdint.h>

typedef __attribute__((ext_vector_type(4))) float f32x4;
typedef __attribute__((ext_vector_type(8))) short s16x8;

typedef const __attribute__((address_space(1))) void* gas_ptr;
typedef __attribute__((address_space(3))) void* las_ptr;

__device__ __forceinline__ unsigned short f2b(float f) {
    union { float f; unsigned u; } v; v.f = f;
    unsigned r = v.u + 0x7fffu + ((v.u >> 16) & 1u);
    return (unsigned short)(r >> 16);
}

__device__ __forceinline__ unsigned pack2(float f0, float f1) {
    union { float f; unsigned u; } a, b;
    a.f = f0; b.f = f1;
    return __builtin_amdgcn_perm(b.u + 0x8000u, a.u + 0x8000u, 0x07060302u);
}

// ---------------------------------------------------------------------------
__global__ void cast2_bf16_k(const float* __restrict__ a, unsigned short* __restrict__ da,
                             const float* __restrict__ b, unsigned short* __restrict__ db,
                             int n4) {
    int i = blockIdx.x * blockDim.x + threadIdx.x;
    int stride = gridDim.x * blockDim.x;
    for (; i < n4; i += stride) {
        float4 va = ((const float4*)a)[i];
        ushort4 pa; pa.x = f2b(va.x); pa.y = f2b(va.y); pa.z = f2b(va.z); pa.w = f2b(va.w);
        ((ushort4*)da)[i] = pa;
        float4 vb = ((const float4*)b)[i];
        ushort4 pb; pb.x = f2b(vb.x); pb.y = f2b(vb.y); pb.z = f2b(vb.z); pb.w = f2b(vb.w);
        ((ushort4*)db)[i] = pb;
    }
}

__global__ void relu_cast_k(const float* __restrict__ s, unsigned short* __restrict__ d, int n4) {
    int i = blockIdx.x * blockDim.x + threadIdx.x;
    int stride = gridDim.x * blockDim.x;
    for (; i < n4; i += stride) {
        float4 v = ((const float4*)s)[i];
        ushort4 p;
        p.x = f2b(fmaxf(v.x, 0.f)); p.y = f2b(fmaxf(v.y, 0.f));
        p.z = f2b(fmaxf(v.z, 0.f)); p.w = f2b(fmaxf(v.w, 0.f));
        ((ushort4*)d)[i] = p;
    }
}

__global__ void transpose_w_k(const float* __restrict__ W1, const float* __restrict__ W2,
                              const float* __restrict__ W3, const float* __restrict__ W4,
                              unsigned short* __restrict__ W1t, unsigned short* __restrict__ W2t,
                              unsigned short* __restrict__ W3t, unsigned short* __restrict__ W4t) {
    __shared__ float tile[32][33];
    const float* src; unsigned short* dst; int R, C;
    switch (blockIdx.z) {
        case 0: src = W1; dst = W1t; R = 256; C = 128; break;
        case 1: src = W2; dst = W2t; R = 128; C = 128; break;
        case 2: src = W3; dst = W3t; R = 128; C = 128; break;
        default: src = W4; dst = W4t; R = 128; C = 128; break;
    }
    int c0 = blockIdx.x * 32, r0 = blockIdx.y * 32;
    if (r0 >= R) return;
    int tx = threadIdx.x & 31, ty = threadIdx.x >> 5;
    #pragma unroll
    for (int rr = ty; rr < 32; rr += 8)
        tile[rr][tx] = src[(size_t)(r0 + rr) * C + c0 + tx];
    __syncthreads();
    #pragma unroll
    for (int rr = ty; rr < 32; rr += 8)
        dst[(size_t)(c0 + rr) * R + r0 + tx] = f2b(tile[tx][rr]);
}

// ---------------------------------------------------------------------------
enum { EP_BF16 = 0, EP_T = 1, EP_TFOLD = 2, EP_EXP = 3, EP_OUT2 = 4 };

template<int BM, int BN, int FM, int FN, int EPI>
__global__ void __launch_bounds__(256)
gemm_nt(const unsigned short* __restrict__ A, const unsigned short* __restrict__ B,
        int lda, int ldb, int kchunk,
        float* __restrict__ Cf, unsigned short* __restrict__ Cb,
        unsigned short* __restrict__ Ct, int ldc, int ldct)
{
    __shared__ __align__(16) short As[BM * 32];
    __shared__ __align__(16) short Bs[BN * 32];

    const int t = threadIdx.x;
    const int lane = t & 63;
    const int w = t >> 6;
    const int wr = w >> 1, wc = w & 1;
    const int m0 = blockIdx.x * BM;
    const int n0 = blockIdx.y * BN;
    const int k0 = blockIdx.z * kchunk;

    f32x4 acc[FM][FN];
    #pragma unroll
    for (int i = 0; i < FM; i++)
        #pragma unroll
        for (int j = 0; j < FN; j++) acc[i][j] = (f32x4){0.f, 0.f, 0.f, 0.f};

    const int KT = kchunk >> 5;
    const int mrow = lane & 15;
    const int q8 = (lane >> 4) << 3;

    for (int kt = 0; kt < KT; ++kt) {
        const int kk = k0 + (kt << 5);
        #pragma unroll
        for (int idx = t; idx < BM * 4; idx += 256) {
            const unsigned short* g = A + (size_t)(m0 + (idx >> 2)) * lda + kk + ((idx & 3) << 3);
            __builtin_amdgcn_global_load_lds((gas_ptr)g, (las_ptr)(As + idx * 8), 16, 0, 0);
        }
        #pragma unroll
        for (int idx = t; idx < BN * 4; idx += 256) {
            const unsigned short* g = B + (size_t)(n0 + (idx >> 2)) * ldb + kk + ((idx & 3) << 3);
            __builtin_amdgcn_global_load_lds((gas_ptr)g, (las_ptr)(Bs + idx * 8), 16, 0, 0);
        }
        __syncthreads();

        s16x8 af[FM], bfr[FN];
        #pragma unroll
        for (int i = 0; i < FM; i++)
            af[i] = *(const s16x8*)(const void*)(As + (wr * FM * 16 + i * 16 + mrow) * 32 + q8);
        #pragma unroll
        for (int j = 0; j < FN; j++)
            bfr[j] = *(const s16x8*)(const void*)(Bs + (wc * FN * 16 + j * 16 + mrow) * 32 + q8);
        #pragma unroll
        for (int i = 0; i < FM; i++)
            #pragma unroll
            for (int j = 0; j < FN; j++)
                acc[i][j] = __builtin_amdgcn_mfma_f32_16x16x32_bf16(af[i], bfr[j], acc[i][j], 0, 0, 0);
        __syncthreads();
    }

    const int cn = lane & 15;
    const int q4 = (lane >> 4) << 2;
    #pragma unroll
    for (int i = 0; i < FM; i++) {
        const int mb = m0 + wr * FM * 16 + i * 16 + q4;
        #pragma unroll
        for (int j = 0; j < FN; j++) {
            const int nn = n0 + wc * FN * 16 + j * 16 + cn;
            if constexpr (EPI == EP_BF16) {
                #pragma unroll
                for (int r = 0; r < 4; r++)
                    Cb[(size_t)(mb + r) * ldc + nn] = f2b(acc[i][j][r]);
            } else if constexpr (EPI == EP_T) {
                ushort4 p;
                p.x = f2b(acc[i][j][0]); p.y = f2b(acc[i][j][1]);
                p.z = f2b(acc[i][j][2]); p.w = f2b(acc[i][j][3]);
                *(ushort4*)(void*)(Ct + (size_t)nn * ldct + mb) = p;
            } else if constexpr (EPI == EP_TFOLD) {
                ushort4 p;
                p.x = f2b(acc[i][j][0]); p.y = f2b(acc[i][j][1]);
                p.z = f2b(acc[i][j][2]); p.w = f2b(acc[i][j][3]);
                const int trow = nn + ((mb >> 12) << 7);
                *(ushort4*)(void*)(Ct + (size_t)trow * ldct + (mb & 4095)) = p;
            } else if constexpr (EPI == EP_EXP) {
                #pragma unroll
                for (int r = 0; r < 4; r++) {
                    float v = __expf(acc[i][j][r]);
                    Cf[(size_t)(mb + r) * ldc + nn] = v;
                    Cb[(size_t)(mb + r) * ldc + nn] = f2b(v);
                }
            } else if constexpr (EPI == EP_OUT2) {
                const size_t off = (size_t)(nn & 127) + ((nn >> 7) ? (size_t)4096 * 128 : 0);
                #pragma unroll
                for (int r = 0; r < 4; r++)
                    atomicAdd(Cf + (size_t)(mb + r) * 128 + off, acc[i][j][r]);
            }
        }
    }
}

// ---------------------------------------------------------------------------
// fused P = Xs2@W3 (y=1) and ZcatT = fold((X2@W4)^T) (y=0); BM=32 BN=128 K=128
__global__ void __launch_bounds__(256)
pz_fused(const unsigned short* __restrict__ X2,
         const unsigned short* __restrict__ W3t, const unsigned short* __restrict__ W4t,
         unsigned short* __restrict__ Pb, unsigned short* __restrict__ ZcatT)
{
    const bool isP = (blockIdx.y == 1);
    if (isP && blockIdx.x >= 128) return;
    const unsigned short* B = isP ? W3t : W4t;

    __shared__ __align__(16) short As[32 * 32];
    __shared__ __align__(16) short Bs[128 * 32];

    const int t = threadIdx.x;
    const int lane = t & 63;
    const int w = t >> 6;
    const int wr = w >> 1, wc = w & 1;
    const int m0 = blockIdx.x * 32;

    f32x4 acc[4];
    #pragma unroll
    for (int j = 0; j < 4; j++) acc[j] = (f32x4){0.f, 0.f, 0.f, 0.f};

    const int mrow = lane & 15;
    const int q8 = (lane >> 4) << 3;

    for (int kt = 0; kt < 4; ++kt) {
        const int kk = kt << 5;
        if (t < 128) {
            const unsigned short* g = X2 + (size_t)(m0 + (t >> 2)) * 128 + kk + ((t & 3) << 3);
            __builtin_amdgcn_global_load_lds((gas_ptr)g, (las_ptr)(As + t * 8), 16, 0, 0);
        }
        #pragma unroll
        for (int idx = t; idx < 512; idx += 256) {
            const unsigned short* g = B + (size_t)(idx >> 2) * 128 + kk + ((idx & 3) << 3);
            __builtin_amdgcn_global_load_lds((gas_ptr)g, (las_ptr)(Bs + idx * 8), 16, 0, 0);
        }
        __syncthreads();

        s16x8 af = *(const s16x8*)(const void*)(As + (wr * 16 + mrow) * 32 + q8);
        #pragma unroll
        for (int j = 0; j < 4; j++) {
            s16x8 bf = *(const s16x8*)(const void*)(Bs + (wc * 64 + j * 16 + mrow) * 32 + q8);
            acc[j] = __builtin_amdgcn_mfma_f32_16x16x32_bf16(af, bf, acc[j], 0, 0, 0);
        }
        __syncthreads();
    }

    const int cn = lane & 15;
    const int q4 = (lane >> 4) << 2;
    const int mb = m0 + wr * 16 + q4;
    #pragma unroll
    for (int j = 0; j < 4; j++) {
        const int nn = wc * 64 + j * 16 + cn;
        if (isP) {
            #pragma unroll
            for (int r = 0; r < 4; r++)
                Pb[(size_t)(mb + r) * 128 + nn] = f2b(acc[j][r]);
        } else {
            ushort4 p;
            p.x = f2b(acc[j][0]); p.y = f2b(acc[j][1]);
            p.z = f2b(acc[j][2]); p.w = f2b(acc[j][3]);
            const int trow = nn + ((mb >> 12) << 7);
            *(ushort4*)(void*)(ZcatT + (size_t)trow * 4096 + (mb & 4095)) = p;
        }
    }
}

// ---------------------------------------------------------------------------
// fp32-A NT GEMM with split-K atomics; A packed to bf16 in-register.
__global__ void __launch_bounds__(256)
gemm_a32_nt(const float* __restrict__ A, const float* __restrict__ A2,
            const unsigned short* __restrict__ B, const unsigned short* __restrict__ B2,
            int Mhalf, int lda, int ldb, int kchunk, float* __restrict__ Cf, int ldc)
{
    __shared__ __align__(16) float As[128 * 32];   // 16 KB
    __shared__ __align__(16) short Bs[128 * 32];   // 8 KB

    const int t = threadIdx.x;
    const int lane = t & 63;
    const int w = t >> 6;
    const int wr = w >> 1, wc = w & 1;
    const int m0 = blockIdx.x * 128;
    const int n0 = blockIdx.y * 128;
    const int k0 = blockIdx.z * kchunk;

    const float* Ap = A;
    const unsigned short* Bp = B;
    int am0 = m0;
    if (m0 >= Mhalf) { Ap = A2; Bp = B2; am0 = m0 - Mhalf; }

    f32x4 acc[4][4];
    #pragma unroll
    for (int i = 0; i < 4; i++)
        #pragma unroll
        for (int j = 0; j < 4; j++) acc[i][j] = (f32x4){0.f, 0.f, 0.f, 0.f};

    const int KT = kchunk >> 5;
    const int mrow = lane & 15;
    const int q8 = (lane >> 4) << 3;
    const int q2 = (lane >> 4) << 1;

    for (int kt = 0; kt < KT; ++kt) {
        const int kk = k0 + (kt << 5);
        #pragma unroll
        for (int it = 0; it < 4; ++it) {
            int idx = it * 256 + t;
            int row = idx >> 3, grp = idx & 7;
            const float* g = Ap + (size_t)(am0 + row) * lda + kk + ((grp ^ (row & 7)) << 2);
            __builtin_amdgcn_global_load_lds((gas_ptr)g, (las_ptr)(As + idx * 4), 16, 0, 0);
        }
        #pragma unroll
        for (int it = 0; it < 2; ++it) {
            int idx = it * 256 + t;
            const unsigned short* g = Bp + (size_t)(n0 + (idx >> 2)) * ldb + kk + ((idx & 3) << 3);
            __builtin_amdgcn_global_load_lds((gas_ptr)g, (las_ptr)(Bs + idx * 8), 16, 0, 0);
        }
        __syncthreads();

        s16x8 af[4], bfr[4];
        #pragma unroll
        for (int i = 0; i < 4; i++) {
            const int r = wr * 64 + i * 16 + mrow;
            const f32x4 lo = *(const f32x4*)(const void*)(As + r * 32 + ((q2 ^ (r & 7)) << 2));
            const f32x4 hi = *(const f32x4*)(const void*)(As + r * 32 + (((q2 | 1) ^ (r & 7)) << 2));
            union { s16x8 v; unsigned u[4]; } pk;
            pk.u[0] = pack2(lo[0], lo[1]); pk.u[1] = pack2(lo[2], lo[3]);
            pk.u[2] = pack2(hi[0], hi[1]); pk.u[3] = pack2(hi[2], hi[3]);
            af[i] = pk.v;
        }
        #pragma unroll
        for (int j = 0; j < 4; j++)
            bfr[j] = *(const s16x8*)(const void*)(Bs + (wc * 64 + j * 16 + mrow) * 32 + q8);
        #pragma unroll
        for (int i = 0; i < 4; i++)
            #pragma unroll
            for (int j = 0; j < 4; j++)
                acc[i][j] = __builtin_amdgcn_mfma_f32_16x16x32_bf16(af[i], bfr[j], acc[i][j], 0, 0, 0);
        __syncthreads();
    }

    const int cn = lane & 15;
    const int q4 = (lane >> 4) << 2;
    #pragma unroll
    for (int i = 0; i < 4; i++) {
        const int mb = m0 + wr * 64 + i * 16 + q4;
        #pragma unroll
        for (int j = 0; j < 4; j++) {
            const int nn = n0 + wc * 64 + j * 16 + cn;
            #pragma unroll
            for (int r = 0; r < 4; r++)
                atomicAdd(Cf + (size_t)(mb + r) * ldc + nn, acc[i][j][r]);
        }
    }
}

// ---------------------------------------------------------------------------
extern "C" void kernel_launch(void* const* d_in, const int* in_sizes, int n_in,
                              void* d_out, int out_size, void* d_ws, size_t ws_size,
                              hipStream_t stream) {
    const int N = 4096;
    const float* A_s = (const float*)d_in[0];
    const float* X_s = (const float*)d_in[1];
    const float* A_t = (const float*)d_in[2];
    const float* X_t = (const float*)d_in[3];
    const float* W1  = (const float*)d_in[4];
    const float* W2  = (const float*)d_in[5];
    const float* W3  = (const float*)d_in[6];
    const float* W4  = (const float*)d_in[7];

    float* out   = (float*)d_out;
    float* S_out = out + (size_t)2 * N * 128;

    char* ws = (char*)d_ws;
    unsigned short* Xcatb = (unsigned short*)(ws + 0);          // 4 MB [8192x256]
    unsigned short* W1t   = (unsigned short*)(ws + 4194304);
    unsigned short* W2t   = (unsigned short*)(ws + 4259840);
    unsigned short* W3t   = (unsigned short*)(ws + 4292608);
    unsigned short* W4t   = (unsigned short*)(ws + 4325376);
    unsigned short* Y1T   = (unsigned short*)(ws + 4718592);    // 2 MB [128x8192]
    float*          Pf    = (float*)(ws + 7340032);             // 4 MB [8192x128] f32 partials
    unsigned short* X1b   = (unsigned short*)(ws + 11534336);   // 2 MB [8192x128]
    unsigned short* X2b   = (unsigned short*)(ws + 13631488);   // 2 MB [8192x128]
    unsigned short* Pb    = (unsigned short*)(ws + 15728640);   // 1 MB [4096x128]
    unsigned short* ZcatT = (unsigned short*)(ws + 16777216);   // 2 MB [256x4096]
    unsigned short* Sb    = (unsigned short*)(ws + 18874368);   // 32 MB [4096x4096]
    unsigned short* Xt2b  = X2b + (size_t)N * 128;

    cast2_bf16_k<<<512, 256, 0, stream>>>(X_s, Xcatb, X_t, Xcatb + (size_t)N * 256, N * 256 / 4);
    transpose_w_k<<<dim3(4, 8, 4), 256, 0, stream>>>(W1, W2, W3, W4, W1t, W2t, W3t, W4t);

    // Y1 = Xcat @ W1, transposed [128 x 8192]   M=8192 K=256
    gemm_nt<32, 128, 1, 4, EP_T><<<dim3(256, 1, 1), 256, 0, stream>>>(
        Xcatb, W1t, 256, 256, 256, nullptr, nullptr, Y1T, 0, 8192);

    // X1 = relu(Acat @ Y1)   M=8192 N=128 K=4096 splitK=16, A fp32
    hipMemsetAsync(Pf, 0, 4194304, stream);
    gemm_a32_nt<<<dim3(64, 1, 16), 256, 0, stream>>>(
        A_s, A_t, Y1T, Y1T + 4096, 4096, 4096, 8192, 256, Pf, 128);
    relu_cast_k<<<1024, 256, 0, stream>>>(Pf, X1b, 8192 * 128 / 4);

    // Y2 = X1 @ W2, transposed   M=8192 K=128
    gemm_nt<32, 128, 1, 4, EP_T><<<dim3(256, 1, 1), 256, 0, stream>>>(
        X1b, W2t, 128, 128, 128, nullptr, nullptr, Y1T, 0, 8192);

    // X2 = relu(Acat @ Y2)
    hipMemsetAsync(Pf, 0, 4194304, stream);
    gemm_a32_nt<<<dim3(64, 1, 16), 256, 0, stream>>>(
        A_s, A_t, Y1T, Y1T + 4096, 4096, 4096, 8192, 256, Pf, 128);
    relu_cast_k<<<1024, 256, 0, stream>>>(Pf, X2b, 8192 * 128 / 4);

    // P = Xs2 @ W3 and ZcatT = fold((X2 @ W4)^T) in one dispatch
    pz_fused<<<dim3(256, 2, 1), 256, 0, stream>>>(X2b, W3t, W4t, Pb, ZcatT);

    // S = exp(P @ Xt2^T): fp32 -> d_out, bf16 -> Sb   M=N=4096 K=128
    gemm_nt<128, 128, 4, 4, EP_EXP><<<dim3(32, 32, 1), 256, 0, stream>>>(
        Pb, Xt2b, 128, 128, 128, S_out, Sb, nullptr, 4096, 0);

    // out = S @ Zcat (atomic fp32)   M=4096 N=256 K=4096 splitK=16
    hipMemsetAsync(out, 0, (size_t)2 * N * 128 * 4, stream);
    gemm_nt<128, 128, 4, 4, EP_OUT2><<<dim3(32, 2, 16), 256, 0, stream>>>(
        Sb, ZcatT, 4096, 4096, 256, out, nullptr, nullptr, 256, 0);
}

// Round 4
// 305.509 us; speedup vs baseline: 1.3462x; 1.3462x over previous
//
#include <hip/hip_runtime.h>
#include <stdint.h>

typedef __attribute__((ext_vector_type(4))) float f32x4;
typedef __attribute__((ext_vector_type(8))) short s16x8;

typedef const __attribute__((address_space(1))) void* gas_ptr;
typedef __attribute__((address_space(3))) void* las_ptr;

__device__ __forceinline__ unsigned short f2b(float f) {
    union { float f; unsigned u; } v; v.f = f;
    unsigned r = v.u + 0x7fffu + ((v.u >> 16) & 1u);
    return (unsigned short)(r >> 16);
}

__device__ __forceinline__ unsigned pack2(float f0, float f1) {
    union { float f; unsigned u; } a, b;
    a.f = f0; b.f = f1;
    return __builtin_amdgcn_perm(b.u + 0x8000u, a.u + 0x8000u, 0x07060302u);
}

// ---------------------------------------------------------------------------
__global__ void cast2_bf16_k(const float* __restrict__ a, unsigned short* __restrict__ da,
                             const float* __restrict__ b, unsigned short* __restrict__ db,
                             int n4) {
    int i = blockIdx.x * blockDim.x + threadIdx.x;
    int stride = gridDim.x * blockDim.x;
    for (; i < n4; i += stride) {
        float4 va = ((const float4*)a)[i];
        ushort4 pa; pa.x = f2b(va.x); pa.y = f2b(va.y); pa.z = f2b(va.z); pa.w = f2b(va.w);
        ((ushort4*)da)[i] = pa;
        float4 vb = ((const float4*)b)[i];
        ushort4 pb; pb.x = f2b(vb.x); pb.y = f2b(vb.y); pb.z = f2b(vb.z); pb.w = f2b(vb.w);
        ((ushort4*)db)[i] = pb;
    }
}

// sum 8 partial slices, relu, cast bf16
__global__ void reduce8_relu_cast_k(const float* __restrict__ P, unsigned short* __restrict__ d,
                                    int n4, int slice4) {
    int i = blockIdx.x * blockDim.x + threadIdx.x;
    int stride = gridDim.x * blockDim.x;
    for (; i < n4; i += stride) {
        f32x4 s = ((const f32x4*)P)[i];
        #pragma unroll
        for (int z = 1; z < 8; z++) s += ((const f32x4*)P)[i + (size_t)z * slice4];
        ushort4 p;
        p.x = f2b(fmaxf(s[0], 0.f)); p.y = f2b(fmaxf(s[1], 0.f));
        p.z = f2b(fmaxf(s[2], 0.f)); p.w = f2b(fmaxf(s[3], 0.f));
        ((ushort4*)d)[i] = p;
    }
}

// sum 8 partial slices of [4096 x 256]; fold columns: out[(c>>7)][m][c&127]
__global__ void reduce8_fold_k(const float* __restrict__ P, float* __restrict__ out) {
    const int n4 = 4096 * 256 / 4;   // float4 groups per slice
    int i = blockIdx.x * blockDim.x + threadIdx.x;
    int stride = gridDim.x * blockDim.x;
    for (; i < n4; i += stride) {
        f32x4 s = ((const f32x4*)P)[i];
        #pragma unroll
        for (int z = 1; z < 8; z++) s += ((const f32x4*)P)[i + (size_t)z * n4];
        const int m = i >> 6;          // 64 float4 per row of 256
        const int c = (i & 63) << 2;   // column 0..252
        float* o = out + ((c >> 7) ? (size_t)4096 * 128 : 0) + (size_t)m * 128 + (c & 127);
        *(f32x4*)(void*)o = s;
    }
}

__global__ void transpose_w_k(const float* __restrict__ W1, const float* __restrict__ W2,
                              const float* __restrict__ W3, const float* __restrict__ W4,
                              unsigned short* __restrict__ W1t, unsigned short* __restrict__ W2t,
                              unsigned short* __restrict__ W3t, unsigned short* __restrict__ W4t) {
    __shared__ float tile[32][33];
    const float* src; unsigned short* dst; int R, C;
    switch (blockIdx.z) {
        case 0: src = W1; dst = W1t; R = 256; C = 128; break;
        case 1: src = W2; dst = W2t; R = 128; C = 128; break;
        case 2: src = W3; dst = W3t; R = 128; C = 128; break;
        default: src = W4; dst = W4t; R = 128; C = 128; break;
    }
    int c0 = blockIdx.x * 32, r0 = blockIdx.y * 32;
    if (r0 >= R) return;
    int tx = threadIdx.x & 31, ty = threadIdx.x >> 5;
    #pragma unroll
    for (int rr = ty; rr < 32; rr += 8)
        tile[rr][tx] = src[(size_t)(r0 + rr) * C + c0 + tx];
    __syncthreads();
    #pragma unroll
    for (int rr = ty; rr < 32; rr += 8)
        dst[(size_t)(c0 + rr) * R + r0 + tx] = f2b(tile[tx][rr]);
}

// ---------------------------------------------------------------------------
enum { EP_BF16 = 0, EP_T = 1, EP_TFOLD = 2, EP_EXP = 3, EP_PART = 4 };

template<int BM, int BN, int FM, int FN, int EPI>
__global__ void __launch_bounds__(256)
gemm_nt(const unsigned short* __restrict__ A, const unsigned short* __restrict__ B,
        int lda, int ldb, int kchunk,
        float* __restrict__ Cf, unsigned short* __restrict__ Cb,
        unsigned short* __restrict__ Ct, int ldc, int ldct)
{
    __shared__ __align__(16) short As[BM * 32];
    __shared__ __align__(16) short Bs[BN * 32];

    const int t = threadIdx.x;
    const int lane = t & 63;
    const int w = t >> 6;
    const int wr = w >> 1, wc = w & 1;
    const int m0 = blockIdx.x * BM;
    const int n0 = blockIdx.y * BN;
    const int k0 = blockIdx.z * kchunk;

    f32x4 acc[FM][FN];
    #pragma unroll
    for (int i = 0; i < FM; i++)
        #pragma unroll
        for (int j = 0; j < FN; j++) acc[i][j] = (f32x4){0.f, 0.f, 0.f, 0.f};

    const int KT = kchunk >> 5;
    const int mrow = lane & 15;
    const int q8 = (lane >> 4) << 3;

    for (int kt = 0; kt < KT; ++kt) {
        const int kk = k0 + (kt << 5);
        #pragma unroll
        for (int idx = t; idx < BM * 4; idx += 256) {
            const unsigned short* g = A + (size_t)(m0 + (idx >> 2)) * lda + kk + ((idx & 3) << 3);
            __builtin_amdgcn_global_load_lds((gas_ptr)g, (las_ptr)(As + idx * 8), 16, 0, 0);
        }
        #pragma unroll
        for (int idx = t; idx < BN * 4; idx += 256) {
            const unsigned short* g = B + (size_t)(n0 + (idx >> 2)) * ldb + kk + ((idx & 3) << 3);
            __builtin_amdgcn_global_load_lds((gas_ptr)g, (las_ptr)(Bs + idx * 8), 16, 0, 0);
        }
        __syncthreads();

        s16x8 af[FM], bfr[FN];
        #pragma unroll
        for (int i = 0; i < FM; i++)
            af[i] = *(const s16x8*)(const void*)(As + (wr * FM * 16 + i * 16 + mrow) * 32 + q8);
        #pragma unroll
        for (int j = 0; j < FN; j++)
            bfr[j] = *(const s16x8*)(const void*)(Bs + (wc * FN * 16 + j * 16 + mrow) * 32 + q8);
        #pragma unroll
        for (int i = 0; i < FM; i++)
            #pragma unroll
            for (int j = 0; j < FN; j++)
                acc[i][j] = __builtin_amdgcn_mfma_f32_16x16x32_bf16(af[i], bfr[j], acc[i][j], 0, 0, 0);
        __syncthreads();
    }

    const int cn = lane & 15;
    const int q4 = (lane >> 4) << 2;
    #pragma unroll
    for (int i = 0; i < FM; i++) {
        const int mb = m0 + wr * FM * 16 + i * 16 + q4;
        #pragma unroll
        for (int j = 0; j < FN; j++) {
            const int nn = n0 + wc * FN * 16 + j * 16 + cn;
            if constexpr (EPI == EP_BF16) {
                #pragma unroll
                for (int r = 0; r < 4; r++)
                    Cb[(size_t)(mb + r) * ldc + nn] = f2b(acc[i][j][r]);
            } else if constexpr (EPI == EP_T) {
                ushort4 p;
                p.x = f2b(acc[i][j][0]); p.y = f2b(acc[i][j][1]);
                p.z = f2b(acc[i][j][2]); p.w = f2b(acc[i][j][3]);
                *(ushort4*)(void*)(Ct + (size_t)nn * ldct + mb) = p;
            } else if constexpr (EPI == EP_TFOLD) {
                ushort4 p;
                p.x = f2b(acc[i][j][0]); p.y = f2b(acc[i][j][1]);
                p.z = f2b(acc[i][j][2]); p.w = f2b(acc[i][j][3]);
                const int trow = nn + ((mb >> 12) << 7);
                *(ushort4*)(void*)(Ct + (size_t)trow * ldct + (mb & 4095)) = p;
            } else if constexpr (EPI == EP_EXP) {
                #pragma unroll
                for (int r = 0; r < 4; r++) {
                    float v = __expf(acc[i][j][r]);
                    Cf[(size_t)(mb + r) * ldc + nn] = v;
                    Cb[(size_t)(mb + r) * ldc + nn] = f2b(v);
                }
            } else if constexpr (EPI == EP_PART) {
                // plain stores into per-z partial slice
                float* base = Cf + (size_t)blockIdx.z * ((size_t)4096 * 256);
                #pragma unroll
                for (int r = 0; r < 4; r++)
                    base[(size_t)(mb + r) * ldc + nn] = acc[i][j][r];
            }
        }
    }
}

// ---------------------------------------------------------------------------
// fused P = Xs2@W3 (y=1) and ZcatT = fold((X2@W4)^T) (y=0); BM=32 BN=128 K=128
__global__ void __launch_bounds__(256)
pz_fused(const unsigned short* __restrict__ X2,
         const unsigned short* __restrict__ W3t, const unsigned short* __restrict__ W4t,
         unsigned short* __restrict__ Pb, unsigned short* __restrict__ ZcatT)
{
    const bool isP = (blockIdx.y == 1);
    if (isP && blockIdx.x >= 128) return;
    const unsigned short* B = isP ? W3t : W4t;

    __shared__ __align__(16) short As[32 * 32];
    __shared__ __align__(16) short Bs[128 * 32];

    const int t = threadIdx.x;
    const int lane = t & 63;
    const int w = t >> 6;
    const int wr = w >> 1, wc = w & 1;
    const int m0 = blockIdx.x * 32;

    f32x4 acc[4];
    #pragma unroll
    for (int j = 0; j < 4; j++) acc[j] = (f32x4){0.f, 0.f, 0.f, 0.f};

    const int mrow = lane & 15;
    const int q8 = (lane >> 4) << 3;

    for (int kt = 0; kt < 4; ++kt) {
        const int kk = kt << 5;
        if (t < 128) {
            const unsigned short* g = X2 + (size_t)(m0 + (t >> 2)) * 128 + kk + ((t & 3) << 3);
            __builtin_amdgcn_global_load_lds((gas_ptr)g, (las_ptr)(As + t * 8), 16, 0, 0);
        }
        #pragma unroll
        for (int idx = t; idx < 512; idx += 256) {
            const unsigned short* g = B + (size_t)(idx >> 2) * 128 + kk + ((idx & 3) << 3);
            __builtin_amdgcn_global_load_lds((gas_ptr)g, (las_ptr)(Bs + idx * 8), 16, 0, 0);
        }
        __syncthreads();

        s16x8 af = *(const s16x8*)(const void*)(As + (wr * 16 + mrow) * 32 + q8);
        #pragma unroll
        for (int j = 0; j < 4; j++) {
            s16x8 bf = *(const s16x8*)(const void*)(Bs + (wc * 64 + j * 16 + mrow) * 32 + q8);
            acc[j] = __builtin_amdgcn_mfma_f32_16x16x32_bf16(af, bf, acc[j], 0, 0, 0);
        }
        __syncthreads();
    }

    const int cn = lane & 15;
    const int q4 = (lane >> 4) << 2;
    const int mb = m0 + wr * 16 + q4;
    #pragma unroll
    for (int j = 0; j < 4; j++) {
        const int nn = wc * 64 + j * 16 + cn;
        if (isP) {
            #pragma unroll
            for (int r = 0; r < 4; r++)
                Pb[(size_t)(mb + r) * 128 + nn] = f2b(acc[j][r]);
        } else {
            ushort4 p;
            p.x = f2b(acc[j][0]); p.y = f2b(acc[j][1]);
            p.z = f2b(acc[j][2]); p.w = f2b(acc[j][3]);
            const int trow = nn + ((mb >> 12) << 7);
            *(ushort4*)(void*)(ZcatT + (size_t)trow * 4096 + (mb & 4095)) = p;
        }
    }
}

// ---------------------------------------------------------------------------
// fp32-A NT GEMM, split-K with per-z partial buffers (plain stores, no atomics).
__global__ void __launch_bounds__(256)
gemm_a32_nt(const float* __restrict__ A, const float* __restrict__ A2,
            const unsigned short* __restrict__ B, const unsigned short* __restrict__ B2,
            int Mhalf, int lda, int ldb, int kchunk, float* __restrict__ Cf, int ldc)
{
    __shared__ __align__(16) float As[128 * 32];   // 16 KB
    __shared__ __align__(16) short Bs[128 * 32];   // 8 KB

    const int t = threadIdx.x;
    const int lane = t & 63;
    const int w = t >> 6;
    const int wr = w >> 1, wc = w & 1;
    const int m0 = blockIdx.x * 128;
    const int n0 = blockIdx.y * 128;
    const int k0 = blockIdx.z * kchunk;

    const float* Ap = A;
    const unsigned short* Bp = B;
    int am0 = m0;
    if (m0 >= Mhalf) { Ap = A2; Bp = B2; am0 = m0 - Mhalf; }

    f32x4 acc[4][4];
    #pragma unroll
    for (int i = 0; i < 4; i++)
        #pragma unroll
        for (int j = 0; j < 4; j++) acc[i][j] = (f32x4){0.f, 0.f, 0.f, 0.f};

    const int KT = kchunk >> 5;
    const int mrow = lane & 15;
    const int q8 = (lane >> 4) << 3;
    const int q2 = (lane >> 4) << 1;

    for (int kt = 0; kt < KT; ++kt) {
        const int kk = k0 + (kt << 5);
        #pragma unroll
        for (int it = 0; it < 4; ++it) {
            int idx = it * 256 + t;
            int row = idx >> 3, grp = idx & 7;
            const float* g = Ap + (size_t)(am0 + row) * lda + kk + ((grp ^ (row & 7)) << 2);
            __builtin_amdgcn_global_load_lds((gas_ptr)g, (las_ptr)(As + idx * 4), 16, 0, 0);
        }
        #pragma unroll
        for (int it = 0; it < 2; ++it) {
            int idx = it * 256 + t;
            const unsigned short* g = Bp + (size_t)(n0 + (idx >> 2)) * ldb + kk + ((idx & 3) << 3);
            __builtin_amdgcn_global_load_lds((gas_ptr)g, (las_ptr)(Bs + idx * 8), 16, 0, 0);
        }
        __syncthreads();

        s16x8 af[4], bfr[4];
        #pragma unroll
        for (int i = 0; i < 4; i++) {
            const int r = wr * 64 + i * 16 + mrow;
            const f32x4 lo = *(const f32x4*)(const void*)(As + r * 32 + ((q2 ^ (r & 7)) << 2));
            const f32x4 hi = *(const f32x4*)(const void*)(As + r * 32 + (((q2 | 1) ^ (r & 7)) << 2));
            union { s16x8 v; unsigned u[4]; } pk;
            pk.u[0] = pack2(lo[0], lo[1]); pk.u[1] = pack2(lo[2], lo[3]);
            pk.u[2] = pack2(hi[0], hi[1]); pk.u[3] = pack2(hi[2], hi[3]);
            af[i] = pk.v;
        }
        #pragma unroll
        for (int j = 0; j < 4; j++)
            bfr[j] = *(const s16x8*)(const void*)(Bs + (wc * 64 + j * 16 + mrow) * 32 + q8);
        #pragma unroll
        for (int i = 0; i < 4; i++)
            #pragma unroll
            for (int j = 0; j < 4; j++)
                acc[i][j] = __builtin_amdgcn_mfma_f32_16x16x32_bf16(af[i], bfr[j], acc[i][j], 0, 0, 0);
        __syncthreads();
    }

    // plain stores into per-z partial slice [8192 x 128]
    float* base = Cf + (size_t)blockIdx.z * ((size_t)8192 * 128);
    const int cn = lane & 15;
    const int q4 = (lane >> 4) << 2;
    #pragma unroll
    for (int i = 0; i < 4; i++) {
        const int mb = m0 + wr * 64 + i * 16 + q4;
        #pragma unroll
        for (int j = 0; j < 4; j++) {
            const int nn = n0 + wc * 64 + j * 16 + cn;
            #pragma unroll
            for (int r = 0; r < 4; r++)
                base[(size_t)(mb + r) * ldc + nn] = acc[i][j][r];
        }
    }
}

// ---------------------------------------------------------------------------
extern "C" void kernel_launch(void* const* d_in, const int* in_sizes, int n_in,
                              void* d_out, int out_size, void* d_ws, size_t ws_size,
                              hipStream_t stream) {
    const int N = 4096;
    const float* A_s = (const float*)d_in[0];
    const float* X_s = (const float*)d_in[1];
    const float* A_t = (const float*)d_in[2];
    const float* X_t = (const float*)d_in[3];
    const float* W1  = (const float*)d_in[4];
    const float* W2  = (const float*)d_in[5];
    const float* W3  = (const float*)d_in[6];
    const float* W4  = (const float*)d_in[7];

    float* out   = (float*)d_out;
    float* S_out = out + (size_t)2 * N * 128;

    char* ws = (char*)d_ws;
    unsigned short* Xcatb = (unsigned short*)(ws + 0);          // 4 MB [8192x256]
    unsigned short* W1t   = (unsigned short*)(ws + 4194304);
    unsigned short* W2t   = (unsigned short*)(ws + 4259840);
    unsigned short* W3t   = (unsigned short*)(ws + 4292608);
    unsigned short* W4t   = (unsigned short*)(ws + 4325376);
    unsigned short* Y1T   = (unsigned short*)(ws + 4718592);    // 2 MB [128x8192]
    unsigned short* X1b   = (unsigned short*)(ws + 6815744);    // 2 MB [8192x128]
    unsigned short* X2b   = (unsigned short*)(ws + 8912896);    // 2 MB [8192x128]
    unsigned short* Pb    = (unsigned short*)(ws + 11010048);   // 1 MB [4096x128]
    unsigned short* ZcatT = (unsigned short*)(ws + 12058624);   // 2 MB [256x4096]
    float*          Pf    = (float*)(ws + 14155776);            // 32 MB partials (8 slices)
    unsigned short* Sb    = (unsigned short*)(ws + 47710208);   // 32 MB [4096x4096]
    unsigned short* Xt2b  = X2b + (size_t)N * 128;

    cast2_bf16_k<<<512, 256, 0, stream>>>(X_s, Xcatb, X_t, Xcatb + (size_t)N * 256, N * 256 / 4);
    transpose_w_k<<<dim3(4, 8, 4), 256, 0, stream>>>(W1, W2, W3, W4, W1t, W2t, W3t, W4t);

    // Y1 = Xcat @ W1, transposed [128 x 8192]   M=8192 K=256
    gemm_nt<32, 128, 1, 4, EP_T><<<dim3(256, 1, 1), 256, 0, stream>>>(
        Xcatb, W1t, 256, 256, 256, nullptr, nullptr, Y1T, 0, 8192);

    // X1 = relu(Acat @ Y1)   M=8192 N=128 K=4096 splitK=8 partials, A fp32
    gemm_a32_nt<<<dim3(64, 1, 8), 256, 0, stream>>>(
        A_s, A_t, Y1T, Y1T + 4096, 4096, 4096, 8192, 512, Pf, 128);
    reduce8_relu_cast_k<<<1024, 256, 0, stream>>>(Pf, X1b, 8192 * 128 / 4, 8192 * 128 / 4);

    // Y2 = X1 @ W2, transposed   M=8192 K=128
    gemm_nt<32, 128, 1, 4, EP_T><<<dim3(256, 1, 1), 256, 0, stream>>>(
        X1b, W2t, 128, 128, 128, nullptr, nullptr, Y1T, 0, 8192);

    // X2 = relu(Acat @ Y2)
    gemm_a32_nt<<<dim3(64, 1, 8), 256, 0, stream>>>(
        A_s, A_t, Y1T, Y1T + 4096, 4096, 4096, 8192, 512, Pf, 128);
    reduce8_relu_cast_k<<<1024, 256, 0, stream>>>(Pf, X2b, 8192 * 128 / 4, 8192 * 128 / 4);

    // P = Xs2 @ W3 and ZcatT = fold((X2 @ W4)^T) in one dispatch
    pz_fused<<<dim3(256, 2, 1), 256, 0, stream>>>(X2b, W3t, W4t, Pb, ZcatT);

    // S = exp(P @ Xt2^T): fp32 -> d_out, bf16 -> Sb   M=N=4096 K=128
    gemm_nt<128, 128, 4, 4, EP_EXP><<<dim3(32, 32, 1), 256, 0, stream>>>(
        Pb, Xt2b, 128, 128, 128, S_out, Sb, nullptr, 4096, 0);

    // out = S @ Zcat (split-K partials)   M=4096 N=256 K=4096 splitK=8
    gemm_nt<128, 128, 4, 4, EP_PART><<<dim3(32, 2, 8), 256, 0, stream>>>(
        Sb, ZcatT, 4096, 4096, 512, Pf, nullptr, nullptr, 256, 0);
    reduce8_fold_k<<<1024, 256, 0, stream>>>(Pf, out);
}